// Round 1
// 198.736 us; speedup vs baseline: 1.0463x; 1.0463x over previous
//
#include <hip/hip_runtime.h>
#include <stdint.h>

// LinearAttention MI355X round 5: fuse qkv-GEMM + kv/ksum reduction.
// k/v never touch HBM: computed operand-swapped, bounced through swizzled LDS,
// reduced to kv (64x64/head) via MFMA over the block's 128 pixels + atomics.
// A(x) fragments live in registers across all 24 W-tiles; W double-buffered
// via swizzled global_load_lds. k_kv kernel deleted.
// B=8, DIM=256, HEADS=8, DHEAD=64, HID=512, NPIX=4096.

#define NPIX 4096
#define HIDC 512
#define DIMC 256
#define BATCH 8

typedef __attribute__((ext_vector_type(8))) short bf16x8;
typedef __attribute__((ext_vector_type(4))) float f32x4;
typedef __attribute__((ext_vector_type(16))) float f32x16;

__device__ __forceinline__ float bf2f(unsigned short h) {
    unsigned int u = ((unsigned int)h) << 16; float f;
    __builtin_memcpy(&f, &u, 4); return f;
}
__device__ __forceinline__ unsigned short f2bf(float f) {
    unsigned int u; __builtin_memcpy(&u, &f, 4);
    u += 0x7fffu + ((u >> 16) & 1u);
    return (unsigned short)(u >> 16);
}
__device__ __forceinline__ float elu1(float x) {
    return x > 0.f ? x + 1.f : __expf(x);
}
// async global->LDS, 16B per lane. LDS dest = wave-uniform base + lane*16.
__device__ __forceinline__ void gl16(const unsigned short* g, unsigned short* l) {
    __builtin_amdgcn_global_load_lds(
        (__attribute__((address_space(1))) const void*)g,
        (__attribute__((address_space(3))) void*)l, 16, 0, 0);
}

// ---------------- K0a: weight conversion ----------------
__global__ __launch_bounds__(256) void k_convW(
    const float* __restrict__ Wqkv, const float* __restrict__ Wout,
    unsigned short* __restrict__ Wb, unsigned short* __restrict__ Wob)
{
    int i4 = (blockIdx.x * 256 + threadIdx.x) * 4;
    const int NW1 = 1536 * 256;
    float4 v; unsigned short* dst;
    if (i4 < NW1) { v = *(const float4*)&Wqkv[i4]; dst = Wb + i4; }
    else { int j = i4 - NW1; v = *(const float4*)&Wout[j]; dst = Wob + j; }
    ushort4 o; o.x = f2bf(v.x); o.y = f2bf(v.y); o.z = f2bf(v.z); o.w = f2bf(v.w);
    *(ushort4*)dst = o;
}

// ---------------- K0b: x transpose+convert ----------------
__global__ __launch_bounds__(256) void k_tx(
    const float* __restrict__ x, unsigned short* __restrict__ xT)
{
    __shared__ float tile[32][33];
    const int n0 = blockIdx.x * 32, c0 = blockIdx.y * 32, b = blockIdx.z;
    const int t = threadIdx.x;
    const int r = t >> 3, c4 = (t & 7) * 4;
    float4 v = *(const float4*)&x[((size_t)b * DIMC + c0 + r) * NPIX + n0 + c4];
    tile[r][c4 + 0] = v.x; tile[r][c4 + 1] = v.y;
    tile[r][c4 + 2] = v.z; tile[r][c4 + 3] = v.w;
    __syncthreads();
    ushort4 o;
    unsigned short* op = (unsigned short*)&o;
#pragma unroll
    for (int i = 0; i < 4; i++) op[i] = f2bf(tile[c4 + i][r]);
    *(ushort4*)&xT[((size_t)b * NPIX + n0 + r) * DIMC + c0 + c4] = o;
}

// ---------------- K1: fused qkv GEMM + kv/ksum reduction ----------------
// grid (32 pixel-tiles, 8 batches) = 256 blocks, 256 threads (4 waves, 1 blk/CU).
// Per block: 128 pixels, loop over 24 W-tiles of 64 rows (8 q; then per head
// h: k-tile, v-tile, kv-MFMA over K=128 pixels, atomic reduce).
// A fragments (x) in registers for the whole kernel; W double-buffered in LDS.
// Ws swizzle: LDS chunk c of row r holds global 16B-chunk c ^ (r&7).
// Bounce swizzle: kS/vS [ch][pix] with ushort index ch*128 + (pix ^ ((ch&7)<<3)).

#define COMPUTE_TILE(SWAP, A0, A1)                                             \
    {                                                                          \
        const unsigned short* Wl = &Ws[cur][0];                                \
        _Pragma("unroll")                                                      \
        for (int ks = 0; ks < 16; ks++) {                                      \
            bf16x8 wf = *(const bf16x8*)&Wl[(wn * 32 + l31) * DIMC +           \
                                (((ks * 2 + lhi) ^ (l31 & 7)) * 8)];           \
            if (SWAP) {                                                        \
                A0 = __builtin_amdgcn_mfma_f32_32x32x16_bf16(wf, af[0][ks], A0, 0, 0, 0); \
                A1 = __builtin_amdgcn_mfma_f32_32x32x16_bf16(wf, af[1][ks], A1, 0, 0, 0); \
            } else {                                                           \
                A0 = __builtin_amdgcn_mfma_f32_32x32x16_bf16(af[0][ks], wf, A0, 0, 0, 0); \
                A1 = __builtin_amdgcn_mfma_f32_32x32x16_bf16(af[1][ks], wf, A1, 0, 0, 0); \
            }                                                                  \
        }                                                                      \
    }

__global__ __launch_bounds__(256, 1) void k_fused(
    const unsigned short* __restrict__ xT,   // B x 4096 x 256
    const unsigned short* __restrict__ Wb,   // 1536 x 256
    const float* __restrict__ cmp,           // B x 4096
    const float* __restrict__ csp,
    unsigned short* __restrict__ qT,         // B x 4096 x 512 (pixel-major)
    float* __restrict__ kvp,                 // (B*8) x 64 x 64
    float* __restrict__ ksump)               // (B*8) x 64
{
    const int b  = blockIdx.y;
    const int m0 = blockIdx.x * 128;
    const int t  = threadIdx.x;
    const int wave = t >> 6, lane = t & 63;
    const int wm = wave >> 1, wn = wave & 1;
    const int l31 = lane & 31, lhi = lane >> 5;

    __shared__ unsigned short Ws[2][64 * DIMC];  // 2 x 32 KB W double-buffer
    __shared__ unsigned short kS[64 * 128];      // 16 KB k bounce [ch][pix]
    __shared__ unsigned short vS[64 * 128];      // 16 KB v bounce [ch][pix]

    const float cs = *csp;

    auto stageW = [&](int wr, int buf) {
#pragma unroll
        for (int i = 0; i < 8; i++) {
            const int rowl = wave * 16 + i * 2 + (lane >> 5);
            const int ck = (lane & 31) ^ (rowl & 7);
            gl16(&Wb[(size_t)(wr + rowl) * DIMC + ck * 8],
                 &Ws[buf][(wave * 16 + i * 2) * DIMC]);
        }
    };

    // stage q-tile 0
    stageW(0, 0);

    // A fragments: global -> registers, MFMA frag layout (row=pix, K split by lhi)
    bf16x8 af[2][16];
    {
        const unsigned short* Ab = xT + ((size_t)b * NPIX + m0 + wm * 64) * DIMC;
#pragma unroll
        for (int pt = 0; pt < 2; pt++)
#pragma unroll
            for (int ks = 0; ks < 16; ks++)
                af[pt][ks] = *(const bf16x8*)&Ab[(size_t)(pt * 32 + l31) * DIMC
                                                 + ks * 16 + lhi * 8];
    }

    const float gv0 = 1.f + cs * cmp[(size_t)b * NPIX + m0 + wm * 64 + l31];
    const float gv1 = 1.f + cs * cmp[(size_t)b * NPIX + m0 + wm * 64 + 32 + l31];

    __syncthreads();
    int cur = 0;

    // ---- q phase: tiles 0..7 (W rows nt*64) ----
    for (int nt = 0; nt < 8; nt++) {
        stageW(nt < 7 ? (nt + 1) * 64 : 512, cur ^ 1);
        f32x16 acc0, acc1;
#pragma unroll
        for (int r = 0; r < 16; r++) { acc0[r] = 0.f; acc1[r] = 0.f; }
        COMPUTE_TILE(0, acc0, acc1)
        const int chq = nt * 64 + wn * 32 + l31;
        unsigned short* qg = qT + ((size_t)b * NPIX + m0 + wm * 64) * HIDC + chq;
#pragma unroll
        for (int r = 0; r < 16; r++) {
            const int rp = (r & 3) + 8 * (r >> 2) + 4 * lhi;
            qg[(size_t)rp * HIDC]        = f2bf(elu1(acc0[r]));
            qg[(size_t)(32 + rp) * HIDC] = f2bf(elu1(acc1[r]));
        }
        __syncthreads();
        cur ^= 1;
    }

    // ---- per-head k/v phase ----
    for (int h = 0; h < 8; h++) {
        // k tile (W rows 512 + h*64), operand-swapped: acc rows=ch, cols=pix
        stageW(1024 + h * 64, cur ^ 1);
        f32x16 acc0, acc1;
#pragma unroll
        for (int r = 0; r < 16; r++) { acc0[r] = 0.f; acc1[r] = 0.f; }
        COMPUTE_TILE(1, acc0, acc1)
#pragma unroll
        for (int r = 0; r < 16; r++) {
            const int ch = wn * 32 + (r & 3) + 8 * (r >> 2) + 4 * lhi;
            const int sw = (ch & 7) << 3;
            const int p0 = wm * 64 + l31;
            kS[ch * 128 + (p0 ^ sw)]        = f2bf(elu1(acc0[r]) * gv0);
            kS[ch * 128 + ((p0 + 32) ^ sw)] = f2bf(elu1(acc1[r]) * gv1);
        }
        __syncthreads();   // kS ready; v tile staged
        // ksum: 4 threads per channel, vectorized swizzled reads
        {
            const int ch = t & 63, cb = (t >> 6) * 4;
            float s = 0.f;
#pragma unroll
            for (int j = 0; j < 4; j++) {
                const bf16x8 kr = *(const bf16x8*)&kS[ch * 128 + (((cb + j) ^ (ch & 7)) * 8)];
#pragma unroll
                for (int u = 0; u < 8; u++) s += bf2f(((const unsigned short*)&kr)[u]);
            }
            atomicAdd(&ksump[(size_t)(b * 8 + h) * 64 + ch], s);
        }
        cur ^= 1;

        // v tile (W rows 1024 + h*64)
        if (h < 7) stageW(512 + (h + 1) * 64, cur ^ 1);
#pragma unroll
        for (int r = 0; r < 16; r++) { acc0[r] = 0.f; acc1[r] = 0.f; }
        COMPUTE_TILE(1, acc0, acc1)
#pragma unroll
        for (int r = 0; r < 16; r++) {
            const int ch = wn * 32 + (r & 3) + 8 * (r >> 2) + 4 * lhi;
            const int sw = (ch & 7) << 3;
            const int p0 = wm * 64 + l31;
            vS[ch * 128 + (p0 ^ sw)]        = f2bf(acc0[r]);
            vS[ch * 128 + ((p0 + 32) ^ sw)] = f2bf(acc1[r]);
        }
        __syncthreads();   // vS ready; next k tile staged

        // kv partial for this head: 64x64 over K = 128 pixels; wave tile 32x32
        f32x16 kvacc;
#pragma unroll
        for (int r = 0; r < 16; r++) kvacc[r] = 0.f;
#pragma unroll
        for (int pk = 0; pk < 8; pk++) {
            const int co = (((pk * 2 + lhi) ^ (l31 & 7)) * 8);
            const bf16x8 kf = *(const bf16x8*)&kS[(wm * 32 + l31) * 128 + co];
            const bf16x8 vf = *(const bf16x8*)&vS[(wn * 32 + l31) * 128 + co];
            kvacc = __builtin_amdgcn_mfma_f32_32x32x16_bf16(kf, vf, kvacc, 0, 0, 0);
        }
        __syncthreads();   // kS/vS free for next head; atomics overlap next tile
        float* kvb = kvp + (size_t)(b * 8 + h) * 4096;
#pragma unroll
        for (int r = 0; r < 16; r++) {
            const int d = wm * 32 + (r & 3) + 8 * (r >> 2) + 4 * lhi;
            atomicAdd(&kvb[d * 64 + wn * 32 + l31], kvacc[r]);
        }
        cur ^= 1;
    }
}

// ---------------- K3: out = z * kv^T q  (32x32x16, K=d=64) ----------------
#define LS3 72
__global__ __launch_bounds__(256) void k_out(
    const unsigned short* __restrict__ qT,   // B x 4096 x 512
    const float* __restrict__ kv, const float* __restrict__ ksum,
    unsigned short* __restrict__ outT)       // B x 4096 x 512
{
    const int bh = blockIdx.y, p0 = blockIdx.x * 128;
    const int b = bh >> 3, h = bh & 7;
    const int t = threadIdx.x, wave = t >> 6, lane = t & 63;
    const int l31 = lane & 31, lhi = lane >> 5;

    __shared__ unsigned short Aq[128 * LS3];  // [pixel][d]
    __shared__ unsigned short Bv[96 * LS3];   // [n][d]: 0..63 kvT, 64 hi, 65 lo, 66..95 zero

    const unsigned short* qg = qT + ((size_t)b * NPIX + p0) * HIDC + h * 64;
#pragma unroll
    for (int i = 0; i < 4; i++) {
        int idx = t + i * 256;
        int row = idx >> 3, c8 = (idx & 7) * 8;
        *(uint4*)&Aq[row * LS3 + c8] = *(const uint4*)&qg[(size_t)row * HIDC + c8];
    }
    const float* kvg = kv + (size_t)bh * 4096;
#pragma unroll
    for (int i = 0; i < 16; i++) {
        int idx = t + i * 256;
        int d = idx >> 6, e = idx & 63;
        Bv[e * LS3 + d] = f2bf(kvg[idx]);
    }
    if (t < 64) {
        float ksv = ksum[bh * 64 + t];
        unsigned short hi = f2bf(ksv);
        Bv[64 * LS3 + t] = hi;
        Bv[65 * LS3 + t] = f2bf(ksv - bf2f(hi));
    }
    for (int i = t; i < 30 * 64; i += 256)
        Bv[(66 + (i >> 6)) * LS3 + (i & 63)] = 0;
    __syncthreads();

    f32x16 acc[3];
#pragma unroll
    for (int j = 0; j < 3; j++)
#pragma unroll
        for (int r = 0; r < 16; r++) acc[j][r] = 0.f;

#pragma unroll
    for (int ksub = 0; ksub < 4; ksub++) {
        const int koff = ksub * 16 + lhi * 8;
        bf16x8 af = *(const bf16x8*)&Aq[(wave * 32 + l31) * LS3 + koff];
#pragma unroll
        for (int nf = 0; nf < 3; nf++) {
            bf16x8 bfg = *(const bf16x8*)&Bv[(nf * 32 + l31) * LS3 + koff];
            acc[nf] = __builtin_amdgcn_mfma_f32_32x32x16_bf16(af, bfg, acc[nf], 0, 0, 0);
        }
    }

    unsigned short* og = outT + ((size_t)b * NPIX + p0 + wave * 32) * HIDC + h * 64;
#pragma unroll
    for (int r = 0; r < 16; r++) {
        float hi = __shfl(acc[2][r], lane & 32);
        float lo = __shfl(acc[2][r], (lane & 32) | 1);
        float z = 1.f / (hi + lo + 1e-6f);
        int prow = (r & 3) + 8 * (r >> 2) + 4 * lhi;
#pragma unroll
        for (int nf = 0; nf < 2; nf++)
            og[(size_t)prow * HIDC + nf * 32 + l31] = f2bf(acc[nf][r] * z);
    }
}

// ---------------- K4: y = outT @ Wob^T + bout (16x16x32, async staging) ------
__global__ __launch_bounds__(256) void k_y(
    const unsigned short* __restrict__ outT,  // B x 4096 x 512
    const unsigned short* __restrict__ Wob,   // 256 x 512
    const float* __restrict__ bout,
    float* __restrict__ y)                    // B x 256 x 4096
{
    const int b  = blockIdx.z;
    const int m0 = blockIdx.x * 128;
    const int n0 = blockIdx.y * 128;
    const int t = threadIdx.x;
    const int wave = t >> 6, lane = t & 63;
    const int wm = wave >> 1, wn = wave & 1;
    const int lrow = lane & 15, quad = lane >> 4;

    __shared__ unsigned short As[128 * 64];
    __shared__ unsigned short Bs[128 * 64];

    const unsigned short* Ag = outT + ((size_t)b * NPIX + m0) * HIDC;
    const unsigned short* Bg = Wob + (size_t)n0 * HIDC;

    f32x4 acc[4][4];
#pragma unroll
    for (int i = 0; i < 4; i++)
#pragma unroll
        for (int j = 0; j < 4; j++) acc[i][j] = (f32x4){0.f, 0.f, 0.f, 0.f};

    const int r8  = lane >> 3;
    const int jg8 = (((lane & 7) ^ r8) & 7) * 8;
    const int xswA = (lrow & 7);

    for (int k0 = 0; k0 < HIDC; k0 += 64) {
#pragma unroll
        for (int i = 0; i < 4; i++) {
            const int rowg = wave * 32 + i * 8;
            gl16(&Ag[(size_t)(rowg + r8) * HIDC + k0 + jg8], &As[rowg * 64]);
            gl16(&Bg[(size_t)(rowg + r8) * HIDC + k0 + jg8], &Bs[rowg * 64]);
        }
        __syncthreads();
#pragma unroll
        for (int ksb = 0; ksb < 2; ksb++) {
            bf16x8 af[4], bfr[4];
#pragma unroll
            for (int mt = 0; mt < 4; mt++) {
                const int row = wm * 64 + mt * 16 + lrow;
                af[mt] = *(const bf16x8*)&As[row * 64 + (((ksb * 4 + quad) ^ xswA)) * 8];
            }
#pragma unroll
            for (int nt = 0; nt < 4; nt++) {
                const int row = wn * 64 + nt * 16 + lrow;
                bfr[nt] = *(const bf16x8*)&Bs[row * 64 + (((ksb * 4 + quad) ^ xswA)) * 8];
            }
#pragma unroll
            for (int mt = 0; mt < 4; mt++)
#pragma unroll
                for (int nt = 0; nt < 4; nt++)
                    acc[mt][nt] = __builtin_amdgcn_mfma_f32_16x16x32_bf16(
                        af[mt], bfr[nt], acc[mt][nt], 0, 0, 0);
        }
        __syncthreads();
    }

#pragma unroll
    for (int mt = 0; mt < 4; mt++) {
        const int pixel0 = m0 + wm * 64 + mt * 16 + quad * 4;
#pragma unroll
        for (int nt = 0; nt < 4; nt++) {
            const int o = n0 + wn * 64 + nt * 16 + lrow;
            const float bias = bout[o];
            f32x4 a = acc[mt][nt];
            float4 st; st.x = a[0] + bias; st.y = a[1] + bias;
            st.z = a[2] + bias; st.w = a[3] + bias;
            *(float4*)&y[((size_t)b * DIMC + o) * NPIX + pixel0] = st;
        }
    }
}

extern "C" void kernel_launch(void* const* d_in, const int* in_sizes, int n_in,
                              void* d_out, int out_size, void* d_ws, size_t ws_size,
                              hipStream_t stream) {
    (void)in_sizes; (void)n_in; (void)out_size; (void)ws_size;
    const float* x    = (const float*)d_in[0];
    const float* cm   = (const float*)d_in[1];
    const float* Wqkv = (const float*)d_in[2];
    const float* Wout = (const float*)d_in[3];
    const float* bout = (const float*)d_in[4];
    const float* csp  = (const float*)d_in[5];
    float* y = (float*)d_out;

    const size_t qn = (size_t)BATCH * HIDC * NPIX;
    char* ws = (char*)d_ws;
    unsigned short* qT   = (unsigned short*)ws;                 ws += qn * 2;
    unsigned short* outT = (unsigned short*)ws;                 ws += qn * 2;
    unsigned short* xT   = outT;  // alias OK: k_tx->k_fused reads xT before k_out writes outT
    float* kvp   = (float*)ws;                                  ws += (size_t)64 * 64 * 64 * 4;
    float* ksump = (float*)ws;                                  ws += (size_t)64 * 64 * 4;
    unsigned short* Wb  = (unsigned short*)ws;                  ws += (size_t)1536 * 256 * 2;
    unsigned short* Wob = (unsigned short*)ws;

    hipMemsetAsync(kvp, 0, ((size_t)64 * 64 * 64 + 64 * 64) * sizeof(float), stream);
    k_convW<<<512, 256, 0, stream>>>(Wqkv, Wout, Wb, Wob);
    k_tx   <<<dim3(128, 8, 8), 256, 0, stream>>>(x, xT);
    k_fused<<<dim3(32, 8),     256, 0, stream>>>(xT, Wb, cm, csp, qT, kvp, ksump);
    k_out  <<<dim3(32, 64),    256, 0, stream>>>(qT, kvp, ksump, outT);
    k_y    <<<dim3(32, 2, 8),  256, 0, stream>>>(outT, Wob, bout, y);
}